// Round 4
// baseline (124.316 us; speedup 1.0000x reference)
//
#include <hip/hip_runtime.h>

#define N_ 64
#define C_ 4
#define D_ 2048
#define K_ 64
#define O_ 256
#define L_ 1985
#define XPAD 2112          // padded x row (D_ + 64)
#define XCOPY 2116         // stride of shifted bf16 copies (shorts)
#define OPITCH 2020        // staging pitch (floats): mod 32 == 4 (bank spread)
#define NTILE 125          // ceil(L_/16)

typedef __attribute__((ext_vector_type(8))) short s16x8;
typedef __attribute__((ext_vector_type(4))) float f32x4;

// lgkmcnt-only barrier: lets global stores stay in flight across it
#define BAR_LGKM() do { \
    asm volatile("s_waitcnt lgkmcnt(0)\n\ts_barrier" ::: "memory"); \
    __builtin_amdgcn_sched_barrier(0); \
} while (0)

__device__ __forceinline__ unsigned short f2bf(float f) {
    union { float f; unsigned u; } v; v.f = f;
    unsigned u = v.u;
    u += 0x7fffu + ((u >> 16) & 1u);   // RNE
    return (unsigned short)(u >> 16);
}

__global__ __launch_bounds__(256) void prep_w(const float* __restrict__ w,
                                              unsigned short* __restrict__ wb,
                                              float* __restrict__ yn) {
    int o = blockIdx.x;
    int tid = threadIdx.x;
    int c = tid >> 6, k = tid & 63;
    size_t idx = (size_t)(o * C_ + c) * K_ + k;
    float v = w[idx];
    wb[idx] = f2bf(v);
    float s = v * v;
    for (int off = 32; off > 0; off >>= 1) s += __shfl_down(s, off, 64);
    if (k == 0) yn[o * C_ + c] = s;
}

// One block per (n,c). 16 waves. Pipeline: compute stage st -> barrier ->
// drain rows to regs -> issue stores (overlap with compute of st+1) -> barrier.
__global__ __launch_bounds__(1024) void shapelet_main(const float* __restrict__ x,
                                                      const unsigned short* __restrict__ wb,
                                                      const float* __restrict__ yn,
                                                      float* __restrict__ out) {
    __shared__ __align__(16) unsigned short xs[4][XCOPY];
    __shared__ float xn[D_];
    __shared__ __align__(16) float ost[16 * OPITCH];

    int nc = blockIdx.x;
    int c = nc & (C_ - 1);
    const float* xrow = x + (size_t)nc * D_;
    int tid = threadIdx.x;

    // phase 0a: x row -> ost (fp32 scratch)
    for (int i = tid; i < XPAD; i += 1024) ost[i] = (i < D_) ? xrow[i] : 0.f;
    __syncthreads();
    // phase 0b: shifted bf16 copies + exact window norms
    for (int i = tid; i < XCOPY; i += 1024) {
        #pragma unroll
        for (int s = 0; s < 4; ++s) {
            int idx = i + s;
            xs[s][i] = (idx < XPAD) ? f2bf(ost[idx]) : (unsigned short)0;
        }
    }
    for (int l = tid; l < D_; l += 1024) {
        float ssum = 0.f;
        #pragma unroll 16
        for (int k = 0; k < K_; ++k) { float v = ost[l + k]; ssum = fmaf(v, v, ssum); }
        xn[l] = ssum;
    }
    __syncthreads();

    int wave = tid >> 6, lane = tid & 63, lr = lane & 15, hi = lane >> 4;
    const unsigned short* xbase = &xs[lr & 3][(lr & ~3) + hi * 8];
    int dj = tid & 63;

    for (int st = 0; st < 16; ++st) {
        // ---- compute stage st: 16 o-rows x full L into ost ----
        int o = st * 16 + lr;
        s16x8 wfr[2];
        #pragma unroll
        for (int kk = 0; kk < 2; ++kk)
            wfr[kk] = *reinterpret_cast<const s16x8*>(
                wb + ((size_t)o * C_ + c) * K_ + kk * 32 + hi * 8);
        float ynv = yn[o * C_ + c];

        for (int t = wave; t < NTILE; t += 16) {
            int l0t = t * 16;
            f32x4 acc = {0.f, 0.f, 0.f, 0.f};
            #pragma unroll
            for (int kk = 0; kk < 2; ++kk) {
                const unsigned long long* p =
                    (const unsigned long long*)(xbase + l0t + kk * 32);
                union { unsigned long long u[2]; s16x8 v; } a;
                a.u[0] = p[0]; a.u[1] = p[1];
                acc = __builtin_amdgcn_mfma_f32_16x16x32_bf16(a.v, wfr[kk], acc, 0, 0, 0);
            }
            f32x4 xv = *reinterpret_cast<const f32x4*>(&xn[l0t + hi * 4]);
            f32x4 r;
            #pragma unroll
            for (int j = 0; j < 4; ++j)
                r[j] = fmaxf(xv[j] + ynv - 2.f * acc[j], 0.f) * (1.f / (float)K_);
            *reinterpret_cast<f32x4*>(&ost[lr * OPITCH + l0t + hi * 4]) = r;
        }
        BAR_LGKM();   // staging complete, visible to all waves

        // ---- drain stage st: wave w pulls row w into regs, then fire stores ----
        float* gb = out + ((size_t)nc * O_ + st * 16 + wave) * L_;
        const float* src = &ost[wave * OPITCH];
        f32x4 rr[8];
        #pragma unroll
        for (int q = 0; q < 8; ++q) {
            int pos = dj * 4 + q * 256;
            if (pos + 4 <= L_) rr[q] = *reinterpret_cast<const f32x4*>(src + pos);
        }
        float tailv = (dj == 0) ? src[L_ - 1] : 0.f;
        #pragma unroll
        for (int q = 0; q < 8; ++q) {
            int pos = dj * 4 + q * 256;
            if (pos + 4 <= L_) __builtin_memcpy(gb + pos, &rr[q], 16);
        }
        if (dj == 0) gb[L_ - 1] = tailv;
        BAR_LGKM();   // drain reads done -> ost reusable; stores stay in flight
    }
}

extern "C" void kernel_launch(void* const* d_in, const int* in_sizes, int n_in,
                              void* d_out, int out_size, void* d_ws, size_t ws_size,
                              hipStream_t stream) {
    const float* x = (const float*)d_in[0];
    const float* w = (const float*)d_in[1];
    float* out = (float*)d_out;

    unsigned short* wb = (unsigned short*)d_ws;                    // 128 KiB
    float* yn = (float*)((char*)d_ws + (size_t)O_ * C_ * K_ * 2);  // 4 KiB

    prep_w<<<O_, 256, 0, stream>>>(w, wb, yn);
    shapelet_main<<<N_ * C_, 1024, 0, stream>>>(x, wb, yn, out);
}